// Round 14
// baseline (140.489 us; speedup 1.0000x reference)
//
#include <hip/hip_runtime.h>
#include <hip/hip_bf16.h>
#include <math.h>

#define NTOK 12800
#define HD 256
#define SOUT (NTOK * HD)

typedef __attribute__((ext_vector_type(8))) short short8_t;
typedef __attribute__((ext_vector_type(4))) float f32x4;

__device__ __forceinline__ unsigned short f2b(float f) {
    union { float f; unsigned u; } v; v.f = f;
    unsigned r = (v.u + 0x7FFFu + ((v.u >> 16) & 1u)) >> 16;
    return (unsigned short)r;
}
__device__ __forceinline__ float b2f(unsigned short s) {
    union { unsigned u; float f; } v; v.u = ((unsigned)s) << 16;
    return v.f;
}
__device__ __forceinline__ void glds16(const void* g, void* l) {
    __builtin_amdgcn_global_load_lds(
        (const __attribute__((address_space(1))) void*)g,
        (__attribute__((address_space(3))) void*)l, 16, 0, 0);
}
__device__ __forceinline__ short8_t add_bf16x8(short8_t a, short8_t b) {
    union { unsigned short u[8]; short8_t v; } ua, ub, r;
    ua.v = a; ub.v = b;
#pragma unroll
    for (int i = 0; i < 8; ++i) r.u[i] = f2b(b2f(ua.u[i]) + b2f(ub.u[i]));
    return r.v;
}
// read 8 fp32, emit bf16 hi + residual lo
__device__ __forceinline__ void split8(const float* s, short8_t* hi, short8_t* lo) {
    const float4 v0 = *reinterpret_cast<const float4*>(s);
    const float4 v1 = *reinterpret_cast<const float4*>(s + 4);
    const float x[8] = { v0.x, v0.y, v0.z, v0.w, v1.x, v1.y, v1.z, v1.w };
    union { unsigned short u[8]; short8_t v; } qh, ql;
#pragma unroll
    for (int c = 0; c < 8; ++c) {
        qh.u[c] = f2b(x[c]);
        ql.u[c] = f2b(x[c] - b2f(qh.u[c]));
    }
    *hi = qh.v;
    *lo = ql.v;
}

// ---------------------------------------------------------------------------
// prepW (unchanged from R10)
// ---------------------------------------------------------------------------
__global__ __launch_bounds__(256) void prepW_kernel(
    const float* __restrict__ W_texp, const float* __restrict__ W_iexp,
    const float* __restrict__ W_mu_t, const float* __restrict__ W_sg_t,
    const float* __restrict__ W_mu_i, const float* __restrict__ W_sg_i,
    const float* __restrict__ W_fuse,
    unsigned short* __restrict__ wt_t, unsigned short* __restrict__ wt_i,
    unsigned short* __restrict__ wt_f,
    unsigned short* __restrict__ wpk_th, unsigned short* __restrict__ wpk_tl,
    unsigned short* __restrict__ wpk_ih, unsigned short* __restrict__ wpk_il)
{
    const int z = blockIdx.y;
    const float* src;
    unsigned short* dsth;
    unsigned short* dstl = nullptr;
    int dstride = 256, koff = 0, rowoff = 0;
    if (z < 8)       { src = W_texp + (size_t)z * 65536;       dsth = wt_t + (size_t)z * 65536; }
    else if (z < 16) { src = W_iexp + (size_t)(z - 8) * 65536; dsth = wt_i + (size_t)(z - 8) * 65536; }
    else if (z == 16){ src = W_mu_t; dsth = wpk_th; dstl = wpk_tl; }
    else if (z == 17){ src = W_sg_t; dsth = wpk_th; dstl = wpk_tl; rowoff = 256; }
    else if (z == 18){ src = W_mu_i; dsth = wpk_ih; dstl = wpk_il; }
    else if (z == 19){ src = W_sg_i; dsth = wpk_ih; dstl = wpk_il; rowoff = 256; }
    else if (z == 20){ src = W_fuse;         dsth = wt_f; dstride = 512; koff = 0;   }
    else             { src = W_fuse + 65536; dsth = wt_f; dstride = 512; koff = 256; }

    const int tk = (blockIdx.x >> 2) * 64;
    const int td = (blockIdx.x & 3) * 64;
    __shared__ float T[64][68];
    const int t = threadIdx.x;
    {
        const int r = t >> 2, c0 = (t & 3) * 16;
        const float* s = &src[(size_t)(tk + r) * 256 + td + c0];
#pragma unroll
        for (int j = 0; j < 4; ++j)
            *reinterpret_cast<float4*>(&T[r][c0 + j * 4]) =
                *reinterpret_cast<const float4*>(&s[j * 4]);
    }
    __syncthreads();
    {
        const int d = t & 63, kc = (t >> 6) * 16;
        union { unsigned short s[16]; short8_t v[2]; } uh, ul;
#pragma unroll
        for (int j = 0; j < 16; ++j) {
            const float x = T[kc + j][d];
            uh.s[j] = f2b(x);
            ul.s[j] = f2b(x - b2f(uh.s[j]));
        }
        unsigned short* p = &dsth[(size_t)(rowoff + td + d) * dstride + koff + tk + kc];
        *reinterpret_cast<short8_t*>(p) = uh.v[0];
        *reinterpret_cast<short8_t*>(p + 8) = uh.v[1];
        if (dstl) {
            unsigned short* q = &dstl[(size_t)(rowoff + td + d) * 256 + tk + kc];
            *reinterpret_cast<short8_t*>(q) = ul.v[0];
            *reinterpret_cast<short8_t*>(q + 8) = ul.v[1];
        }
    }
}

// ---------------------------------------------------------------------------
// reparam (exact R10 version): packed [Wmu|Wsg], 64M x 128Npacked, 3-pass
// split-precision MFMA, in-register A split. grid (200, 4, 2).
// ---------------------------------------------------------------------------
__global__ __launch_bounds__(256) void reparam_mfma_kernel(
    const float* __restrict__ text, const float* __restrict__ img,
    const unsigned short* __restrict__ wpk_th, const unsigned short* __restrict__ wpk_tl,
    const unsigned short* __restrict__ wpk_ih, const unsigned short* __restrict__ wpk_il,
    const float* __restrict__ b_mu_t, const float* __restrict__ b_sg_t,
    const float* __restrict__ b_mu_i, const float* __restrict__ b_sg_i,
    float* __restrict__ o_tmu, float* __restrict__ o_tsig,
    float* __restrict__ o_imu, float* __restrict__ o_isig)
{
    const int mod = blockIdx.z;
    const float* A = mod ? img : text;
    const unsigned short* Wh = mod ? wpk_ih : wpk_th;
    const unsigned short* Wl = mod ? wpk_il : wpk_tl;
    const float* bmu = mod ? b_mu_i : b_mu_t;
    const float* bsg = mod ? b_sg_i : b_sg_t;
    float* omu = mod ? o_imu : o_tmu;
    float* osg = mod ? o_isig : o_tsig;

    __shared__ __align__(16) unsigned short AhS[2][4][64][8];
    __shared__ __align__(16) unsigned short AlS[2][4][64][8];
    __shared__ __align__(16) unsigned short BhS[2][4][128][8];
    __shared__ __align__(16) unsigned short BlS[2][4][128][8];

    const int tid = threadIdx.x;
    const int lane = tid & 63;
    const int w = tid >> 6;
    const int wr = w >> 1, wc = w & 1;
    const int lg = lane >> 4;
    const int lr = lane & 15;
    const int m0 = blockIdx.x * 64;
    const int n0 = blockIdx.y * 128;

    const int ar = tid >> 2, akc = tid & 3;
    const int bn = tid >> 1, bk0 = (tid & 1) * 2;

    {   // prologue: ks = 0
        short8_t h0, l0;
        split8(&A[(size_t)(m0 + ar) * HD + akc * 8], &h0, &l0);
        *reinterpret_cast<short8_t*>(&AhS[0][akc][ar][0]) = h0;
        *reinterpret_cast<short8_t*>(&AlS[0][akc][ar][0]) = l0;
#pragma unroll
        for (int j = 0; j < 2; ++j) {
            const int kc = bk0 + j;
            *reinterpret_cast<short8_t*>(&BhS[0][kc][bn][0]) =
                *reinterpret_cast<const short8_t*>(&Wh[(size_t)(n0 + bn) * HD + kc * 8]);
            *reinterpret_cast<short8_t*>(&BlS[0][kc][bn][0]) =
                *reinterpret_cast<const short8_t*>(&Wl[(size_t)(n0 + bn) * HD + kc * 8]);
        }
    }
    __syncthreads();

    f32x4 acc[2][4];
#pragma unroll
    for (int mi = 0; mi < 2; ++mi)
#pragma unroll
        for (int ni = 0; ni < 4; ++ni)
            acc[mi][ni] = (f32x4){0.f, 0.f, 0.f, 0.f};

    for (int ks = 0; ks < 8; ++ks) {
        const int cur = ks & 1;
        short8_t rah, ral, rbh[2], rbl[2];
        if (ks < 7) {
            const int k1 = (ks + 1) * 32;
            split8(&A[(size_t)(m0 + ar) * HD + k1 + akc * 8], &rah, &ral);
#pragma unroll
            for (int j = 0; j < 2; ++j) {
                const int kc = bk0 + j;
                rbh[j] = *reinterpret_cast<const short8_t*>(&Wh[(size_t)(n0 + bn) * HD + k1 + kc * 8]);
                rbl[j] = *reinterpret_cast<const short8_t*>(&Wl[(size_t)(n0 + bn) * HD + k1 + kc * 8]);
            }
        }
        short8_t ahf[2], alf[2], bhf[4], blf[4];
#pragma unroll
        for (int mi = 0; mi < 2; ++mi) {
            ahf[mi] = *reinterpret_cast<const short8_t*>(&AhS[cur][lg][wr * 32 + mi * 16 + lr][0]);
            alf[mi] = *reinterpret_cast<const short8_t*>(&AlS[cur][lg][wr * 32 + mi * 16 + lr][0]);
        }
#pragma unroll
        for (int ni = 0; ni < 4; ++ni) {
            bhf[ni] = *reinterpret_cast<const short8_t*>(&BhS[cur][lg][wc * 64 + ni * 16 + lr][0]);
            blf[ni] = *reinterpret_cast<const short8_t*>(&BlS[cur][lg][wc * 64 + ni * 16 + lr][0]);
        }
#pragma unroll
        for (int mi = 0; mi < 2; ++mi)
#pragma unroll
            for (int ni = 0; ni < 4; ++ni) {
                acc[mi][ni] = __builtin_amdgcn_mfma_f32_16x16x32_bf16(ahf[mi], bhf[ni], acc[mi][ni], 0, 0, 0);
                acc[mi][ni] = __builtin_amdgcn_mfma_f32_16x16x32_bf16(ahf[mi], blf[ni], acc[mi][ni], 0, 0, 0);
                acc[mi][ni] = __builtin_amdgcn_mfma_f32_16x16x32_bf16(alf[mi], bhf[ni], acc[mi][ni], 0, 0, 0);
            }
        if (ks < 7) {
            const int nxt = cur ^ 1;
            *reinterpret_cast<short8_t*>(&AhS[nxt][akc][ar][0]) = rah;
            *reinterpret_cast<short8_t*>(&AlS[nxt][akc][ar][0]) = ral;
#pragma unroll
            for (int j = 0; j < 2; ++j) {
                const int kc = bk0 + j;
                *reinterpret_cast<short8_t*>(&BhS[nxt][kc][bn][0]) = rbh[j];
                *reinterpret_cast<short8_t*>(&BlS[nxt][kc][bn][0]) = rbl[j];
            }
        }
        __syncthreads();
    }

    const bool is_sg = (n0 >= 256);
    float bv[4];
    int cc[4];
#pragma unroll
    for (int ni = 0; ni < 4; ++ni) {
        const int dpk = n0 + wc * 64 + ni * 16 + lr;
        cc[ni] = is_sg ? dpk - 256 : dpk;
        bv[ni] = is_sg ? bsg[cc[ni]] : bmu[cc[ni]];
    }
    float* outp = is_sg ? osg : omu;
#pragma unroll
    for (int mi = 0; mi < 2; ++mi)
#pragma unroll
        for (int r = 0; r < 4; ++r) {
            const int row = m0 + wr * 32 + mi * 16 + lg * 4 + r;
#pragma unroll
            for (int ni = 0; ni < 4; ++ni) {
                const float v = acc[mi][ni][r] + bv[ni];
                outp[(size_t)row * HD + cc[ni]] = is_sg ? expf(v) : v;
            }
        }
}

// ---------------------------------------------------------------------------
// gating (exact R10 version)
// ---------------------------------------------------------------------------
__global__ __launch_bounds__(256) void gate_kernel(
    const float* __restrict__ o_tmu, const float* __restrict__ o_tsig,
    const float* __restrict__ o_imu, const float* __restrict__ o_isig,
    const float* __restrict__ noise_t, const float* __restrict__ noise_i,
    const float* __restrict__ Wg, const float* __restrict__ bg,
    unsigned short* __restrict__ tzb, unsigned short* __restrict__ izb,
    unsigned* __restrict__ sel_e, float2* __restrict__ sel_w)
{
    const int mod = blockIdx.y;
    const float* mu    = mod ? o_imu  : o_tmu;
    const float* sig   = mod ? o_isig : o_tsig;
    const float* noise = mod ? noise_i : noise_t;
    unsigned short* zb = mod ? izb : tzb;

    const int lane = threadIdx.x & 63;
    const int n = blockIdx.x * 4 + (threadIdx.x >> 6);
    const size_t off = (size_t)n * HD + lane * 4;
    const float4 m4 = *reinterpret_cast<const float4*>(&mu[off]);
    const float4 s4 = *reinterpret_cast<const float4*>(&sig[off]);
    const float4 n4 = *reinterpret_cast<const float4*>(&noise[off]);
    const float zz[4] = { fmaf(s4.x, n4.x, m4.x), fmaf(s4.y, n4.y, m4.y),
                          fmaf(s4.z, n4.z, m4.z), fmaf(s4.w, n4.w, m4.w) };
    ushort4 zb4;
    zb4.x = f2b(zz[0]); zb4.y = f2b(zz[1]); zb4.z = f2b(zz[2]); zb4.w = f2b(zz[3]);
    *reinterpret_cast<ushort4*>(&zb[off]) = zb4;

    float lg[8];
#pragma unroll
    for (int e = 0; e < 8; ++e) lg[e] = 0.f;
#pragma unroll
    for (int i = 0; i < 4; ++i) {
        const float* wr = &Wg[(size_t)(lane * 4 + i) * 8];
        const float4 w0 = *reinterpret_cast<const float4*>(wr);
        const float4 w1 = *reinterpret_cast<const float4*>(wr + 4);
        lg[0] = fmaf(zz[i], w0.x, lg[0]); lg[1] = fmaf(zz[i], w0.y, lg[1]);
        lg[2] = fmaf(zz[i], w0.z, lg[2]); lg[3] = fmaf(zz[i], w0.w, lg[3]);
        lg[4] = fmaf(zz[i], w1.x, lg[4]); lg[5] = fmaf(zz[i], w1.y, lg[5]);
        lg[6] = fmaf(zz[i], w1.z, lg[6]); lg[7] = fmaf(zz[i], w1.w, lg[7]);
    }
#pragma unroll
    for (int off2 = 32; off2; off2 >>= 1)
#pragma unroll
        for (int e = 0; e < 8; ++e) lg[e] += __shfl_down(lg[e], off2);

    if (lane == 0) {
        float m = -1e30f;
#pragma unroll
        for (int e = 0; e < 8; ++e) { lg[e] += bg[e]; m = fmaxf(m, lg[e]); }
        float p[8], s = 0.f;
#pragma unroll
        for (int e = 0; e < 8; ++e) { p[e] = expf(lg[e] - m); s += p[e]; }
        const float inv_s = 1.f / s;
#pragma unroll
        for (int e = 0; e < 8; ++e) p[e] *= inv_s;
        int e1 = 0;
#pragma unroll
        for (int e = 1; e < 8; ++e) if (p[e] > p[e1]) e1 = e;
        int e2 = (e1 == 0) ? 1 : 0;
#pragma unroll
        for (int e = 0; e < 8; ++e) if (e != e1 && p[e] > p[e2]) e2 = e;
        const float denom = 1.f / (p[e1] + p[e2] + 1e-8f);
        sel_e[(size_t)mod * NTOK + n] = (unsigned)e1 | ((unsigned)e2 << 8);
        sel_w[(size_t)mod * NTOK + n] = make_float2(p[e1] * denom, p[e2] * denom);
    }
}

// ---------------------------------------------------------------------------
// compact (exact R10 version)
// ---------------------------------------------------------------------------
__global__ __launch_bounds__(1024) void compact_kernel(
    const unsigned* __restrict__ sel_e, const float2* __restrict__ sel_w,
    unsigned* __restrict__ idx_list, float* __restrict__ wgt_list,
    unsigned* __restrict__ cnt)
{
    const int seg = blockIdx.x;          // mod*8 + e
    const int mod = seg >> 3;
    const unsigned e = (unsigned)(seg & 7);
    const int tid = threadIdx.x;
    const int wid = tid >> 6, lane = tid & 63;
    __shared__ unsigned wsum[16];

    unsigned off = 0;
    unsigned* dst_i = idx_list + (size_t)seg * NTOK;
    float* dst_w = wgt_list + (size_t)seg * NTOK;

    for (int chunk = 0; chunk < NTOK; chunk += 1024) {
        const int n = chunk + tid;
        const bool valid = (n < NTOK);
        unsigned se = 0;
        float2 wv = make_float2(0.f, 0.f);
        if (valid) {
            se = sel_e[(size_t)mod * NTOK + n];
            wv = sel_w[(size_t)mod * NTOK + n];
        }
#pragma unroll
        for (int slot = 0; slot < 2; ++slot) {
            const unsigned es = slot ? ((se >> 8) & 0xffu) : (se & 0xffu);
            const bool pred = valid && (es == e);
            const unsigned long long mask = __ballot(pred);
            if (lane == 0) wsum[wid] = (unsigned)__popcll(mask);
            __syncthreads();
            unsigned prefix = 0, total = 0;
#pragma unroll
            for (int wI = 0; wI < 16; ++wI) {
                const unsigned c = wsum[wI];
                if (wI < wid) prefix += c;
                total += c;
            }
            if (pred) {
                const unsigned long long lt = ((unsigned long long)1 << lane) - 1ull;
                const unsigned pos = off + prefix + (unsigned)__popcll(mask & lt);
                dst_i[pos] = (unsigned)(n * 2 + slot);
                dst_w[pos] = slot ? wv.y : wv.x;
            }
            off += total;
            __syncthreads();
        }
    }
    if (tid == 0) cnt[seg * 32] = off;
}

// ---------------------------------------------------------------------------
// sparse experts (exact R10 version)
// ---------------------------------------------------------------------------
__global__ __launch_bounds__(256) void expert_sparse_kernel(
    const unsigned short* __restrict__ tzb, const unsigned short* __restrict__ izb,
    const unsigned short* __restrict__ wt_t, const unsigned short* __restrict__ wt_i,
    const float* __restrict__ bx_t, const float* __restrict__ bx_i,
    const unsigned* __restrict__ idx_list, const float* __restrict__ wgt_list,
    const unsigned* __restrict__ cnt,
    unsigned short* __restrict__ slot_t, unsigned short* __restrict__ slot_i)
{
    const int chunk = blockIdx.x;
    const int e  = blockIdx.y >> 1;
    const int nh = blockIdx.y & 1;
    const int mod = blockIdx.z;
    const int seg = mod * 8 + e;
    const unsigned cnt_e = cnt[seg * 32];
    if ((unsigned)(chunk * 128) >= cnt_e) return;

    const unsigned short* Zb = mod ? izb : tzb;
    const unsigned short* Wt = mod ? wt_i : wt_t;
    const float* bx = mod ? bx_i : bx_t;
    unsigned short* outp = mod ? slot_i : slot_t;
    const int n0 = nh * 128;
    const size_t sb = (size_t)seg * NTOK + (size_t)chunk * 128;

    __shared__ __align__(16) unsigned short Ab[2][512][8];
    __shared__ __align__(16) unsigned short Bb[2][512][8];
    __shared__ float gw[128];
    __shared__ unsigned il[128];

    const int tid = threadIdx.x;
    const int lane = tid & 63;
    const int w = tid >> 6;
    const int wr = w >> 1, wc = w & 1;
    const int lg = lane >> 4;
    const int lr = lane & 15;

    if (tid < 128) {
        const bool v = (unsigned)(chunk * 128 + tid) < cnt_e;
        il[tid] = v ? idx_list[sb + tid] : (unsigned)(2 * NTOK);
        gw[tid] = v ? wgt_list[sb + tid] : 0.f;
    }

    const int c0 = w * 64 + lane;
    const int row0 = c0 >> 2,         kc0 = c0 & 3;
    const int row1 = (c0 + 256) >> 2, kc1 = (c0 + 256) & 3;
    const unsigned i0 = ((unsigned)(chunk * 128 + row0) < cnt_e)
                        ? idx_list[sb + row0] : (unsigned)(2 * NTOK);
    const unsigned i1 = ((unsigned)(chunk * 128 + row1) < cnt_e)
                        ? idx_list[sb + row1] : (unsigned)(2 * NTOK);
    const size_t atok0 = (size_t)(i0 >> 1) * HD;
    const size_t atok1 = (size_t)(i1 >> 1) * HD;
    const unsigned short* We_ = Wt + (size_t)e * 65536 + (size_t)n0 * HD;

#define SSTAGE(buf, ks_)                                                       \
    {                                                                          \
        glds16(&Zb[atok0 + (ks_) * 32 + kc0 * 8], &Ab[buf][w * 64][0]);        \
        glds16(&Zb[atok1 + (ks_) * 32 + kc1 * 8], &Ab[buf][256 + w * 64][0]);  \
        glds16(&We_[(size_t)row0 * HD + (ks_) * 32 + kc0 * 8],                 \
               &Bb[buf][w * 64][0]);                                           \
        glds16(&We_[(size_t)row1 * HD + (ks_) * 32 + kc1 * 8],                 \
               &Bb[buf][256 + w * 64][0]);                                     \
    }

    SSTAGE(0, 0);
    __syncthreads();

    f32x4 acc[4][4];
#pragma unroll
    for (int mi = 0; mi < 4; ++mi)
#pragma unroll
        for (int ni = 0; ni < 4; ++ni)
            acc[mi][ni] = (f32x4){0.f, 0.f, 0.f, 0.f};

    for (int ks = 0; ks < 8; ++ks) {
        const int cur = ks & 1;
        if (ks < 7) SSTAGE(cur ^ 1, ks + 1);
        short8_t af[4], bf[4];
#pragma unroll
        for (int mi = 0; mi < 4; ++mi)
            af[mi] = *reinterpret_cast<const short8_t*>(
                &Ab[cur][(wr * 64 + mi * 16 + lr) * 4 + lg][0]);
#pragma unroll
        for (int ni = 0; ni < 4; ++ni)
            bf[ni] = *reinterpret_cast<const short8_t*>(
                &Bb[cur][(wc * 64 + ni * 16 + lr) * 4 + lg][0]);
#pragma unroll
        for (int mi = 0; mi < 4; ++mi)
#pragma unroll
            for (int ni = 0; ni < 4; ++ni)
                acc[mi][ni] = __builtin_amdgcn_mfma_f32_16x16x32_bf16(
                    af[mi], bf[ni], acc[mi][ni], 0, 0, 0);
        __syncthreads();
    }
#undef SSTAGE

    float bv[4];
#pragma unroll
    for (int ni = 0; ni < 4; ++ni)
        bv[ni] = bx[(size_t)e * HD + n0 + wc * 64 + ni * 16 + lr];
#pragma unroll
    for (int mi = 0; mi < 4; ++mi)
#pragma unroll
        for (int r = 0; r < 4; ++r) {
            const int row_local = wr * 64 + mi * 16 + lg * 4 + r;
            const float wv = gw[row_local];
            const size_t tb = (size_t)il[row_local] * HD;
#pragma unroll
            for (int ni = 0; ni < 4; ++ni)
                outp[tb + n0 + wc * 64 + ni * 16 + lr] =
                    f2b(wv * (acc[mi][ni][r] + bv[ni]));
        }
}

// ---------------------------------------------------------------------------
// fuse GEMM + LN + ReLU + residual: BM=32, BN=256 (full rows), K=512.
// Per wave: 16 rows x 128 cols (wr x wc), acc[8]. Row-LN via 16-lane
// shfl_xor partial + 2-half LDS combine. grid = 400 blocks.
// ---------------------------------------------------------------------------
__global__ __launch_bounds__(256) void fusegemm_ln_kernel(
    const unsigned short* __restrict__ slot_t, const unsigned short* __restrict__ slot_i,
    const unsigned short* __restrict__ wtf, const float* __restrict__ bfuse,
    const float* __restrict__ lng, const float* __restrict__ lnb,
    const float* __restrict__ item, float* __restrict__ fusion)
{
    __shared__ __align__(16) unsigned short AS[2][8][32][8];   //  8 KB
    __shared__ __align__(16) unsigned short BS[2][8][256][8];  // 64 KB
    __shared__ float2 part[2][32];                             // 0.5 KB

    const int tid = threadIdx.x;
    const int lane = tid & 63;
    const int w = tid >> 6;
    const int wr = w >> 1, wc = w & 1;
    const int lg = lane >> 4;
    const int lr = lane & 15;
    const int m0 = blockIdx.x * 32;

    const int ar = tid >> 3, akc = tid & 7;   // A: 1 chunk/thread
    const int bn = tid;                       // B: 8 chunks/thread (one row)
    const size_t tb = (size_t)(m0 + ar) * 2 * HD;

    {   // prologue ks=0
        const short8_t s0 = *reinterpret_cast<const short8_t*>(&slot_t[tb + akc * 8]);
        const short8_t s1 = *reinterpret_cast<const short8_t*>(&slot_t[tb + HD + akc * 8]);
        *reinterpret_cast<short8_t*>(&AS[0][akc][ar][0]) = add_bf16x8(s0, s1);
#pragma unroll
        for (int j = 0; j < 8; ++j)
            *reinterpret_cast<short8_t*>(&BS[0][j][bn][0]) =
                *reinterpret_cast<const short8_t*>(&wtf[(size_t)bn * 512 + j * 8]);
    }
    __syncthreads();

    f32x4 acc[8];
#pragma unroll
    for (int ni = 0; ni < 8; ++ni) acc[ni] = (f32x4){0.f, 0.f, 0.f, 0.f};

    for (int ks = 0; ks < 8; ++ks) {
        const int cur = ks & 1;
        short8_t ra, rbv[8];
        if (ks < 7) {
            const int ks2 = ks + 1;
            const unsigned short* sp = (ks2 < 4) ? slot_t : slot_i;
            const int kloc = (ks2 & 3) * 64;
            const short8_t s0 = *reinterpret_cast<const short8_t*>(&sp[tb + kloc + akc * 8]);
            const short8_t s1 = *reinterpret_cast<const short8_t*>(&sp[tb + HD + kloc + akc * 8]);
            ra = add_bf16x8(s0, s1);
#pragma unroll
            for (int j = 0; j < 8; ++j)
                rbv[j] = *reinterpret_cast<const short8_t*>(
                    &wtf[(size_t)bn * 512 + ks2 * 64 + j * 8]);
        }
#pragma unroll
        for (int s = 0; s < 2; ++s) {
            const short8_t af = *reinterpret_cast<const short8_t*>(
                &AS[cur][s * 4 + lg][wr * 16 + lr][0]);
#pragma unroll
            for (int ni = 0; ni < 8; ++ni) {
                const short8_t bf = *reinterpret_cast<const short8_t*>(
                    &BS[cur][s * 4 + lg][wc * 128 + ni * 16 + lr][0]);
                acc[ni] = __builtin_amdgcn_mfma_f32_16x16x32_bf16(af, bf, acc[ni], 0, 0, 0);
            }
        }
        if (ks < 7) {
            const int nxt = cur ^ 1;
            *reinterpret_cast<short8_t*>(&AS[nxt][akc][ar][0]) = ra;
#pragma unroll
            for (int j = 0; j < 8; ++j)
                *reinterpret_cast<short8_t*>(&BS[nxt][j][bn][0]) = rbv[j];
        }
        __syncthreads();
    }

    // bias + row partial sums
    int cc[8];
    float bvv[8];
#pragma unroll
    for (int ni = 0; ni < 8; ++ni) {
        cc[ni] = wc * 128 + ni * 16 + lr;
        bvv[ni] = bfuse[cc[ni]];
    }
#pragma unroll
    for (int r = 0; r < 4; ++r) {
        const int row_l = wr * 16 + lg * 4 + r;
        float s = 0.f, ss = 0.f;
#pragma unroll
        for (int ni = 0; ni < 8; ++ni) {
            const float v = acc[ni][r] + bvv[ni];
            s += v;
            ss = fmaf(v, v, ss);
        }
#pragma unroll
        for (int o = 1; o < 16; o <<= 1) {
            s += __shfl_xor(s, o);
            ss += __shfl_xor(ss, o);
        }
        if (lr == 0) part[wc][row_l] = make_float2(s, ss);
    }
    __syncthreads();

    float lgv[8], lbv[8];
#pragma unroll
    for (int ni = 0; ni < 8; ++ni) {
        lgv[ni] = lng[cc[ni]];
        lbv[ni] = lnb[cc[ni]];
    }
#pragma unroll
    for (int r = 0; r < 4; ++r) {
        const int row_l = wr * 16 + lg * 4 + r;
        const int row = m0 + row_l;
        const float2 p0 = part[0][row_l];
        const float2 p1 = part[1][row_l];
        const float mean = (p0.x + p1.x) * (1.f / 256.f);
        const float var = (p0.y + p1.y) * (1.f / 256.f) - mean * mean;
        const float rstd = rsqrtf(var + 1e-5f);
#pragma unroll
        for (int ni = 0; ni < 8; ++ni) {
            const size_t off = (size_t)row * HD + cc[ni];
            const float v = acc[ni][r] + bvv[ni];
            fusion[off] = fmaxf((v - mean) * rstd * lgv[ni] + lbv[ni], 0.f) + item[off];
        }
    }
}

// ---------------------------------------------------------------------------
extern "C" void kernel_launch(void* const* d_in, const int* in_sizes, int n_in,
                              void* d_out, int out_size, void* d_ws, size_t ws_size,
                              hipStream_t stream)
{
    const float* text    = (const float*)d_in[0];
    const float* img     = (const float*)d_in[1];
    const float* item    = (const float*)d_in[2];
    const float* noise_t = (const float*)d_in[3];
    const float* noise_i = (const float*)d_in[4];
    const float* W_mu_t  = (const float*)d_in[5];
    const float* b_mu_t  = (const float*)d_in[6];
    const float* W_sg_t  = (const float*)d_in[7];
    const float* b_sg_t  = (const float*)d_in[8];
    const float* W_mu_i  = (const float*)d_in[9];
    const float* b_mu_i  = (const float*)d_in[10];
    const float* W_sg_i  = (const float*)d_in[11];
    const float* b_sg_i  = (const float*)d_in[12];
    const float* W_gate  = (const float*)d_in[13];
    const float* b_gate  = (const float*)d_in[14];
    const float* W_texp  = (const float*)d_in[15];
    const float* b_texp  = (const float*)d_in[16];
    const float* W_iexp  = (const float*)d_in[17];
    const float* b_iexp  = (const float*)d_in[18];
    const float* W_fuse  = (const float*)d_in[19];
    const float* b_fuse  = (const float*)d_in[20];
    const float* ln_g    = (const float*)d_in[21];
    const float* ln_b    = (const float*)d_in[22];

    float* out    = (float*)d_out;
    float* fusion = out;
    float* o_tmu  = out + (size_t)SOUT;
    float* o_tsig = out + (size_t)2 * SOUT;
    float* o_imu  = out + (size_t)3 * SOUT;
    float* o_isig = out + (size_t)4 * SOUT;

    const size_t SLOTPAD = (size_t)(2 * NTOK + 256) * HD;
    unsigned short* slot_t = (unsigned short*)d_ws;
    unsigned short* slot_i = slot_t + SLOTPAD;
    unsigned short* tzb    = slot_i + SLOTPAD;
    unsigned short* izb    = tzb + (size_t)SOUT;
    unsigned short* wt_t   = izb + (size_t)SOUT;
    unsigned short* wt_i   = wt_t + (size_t)8 * 65536;
    unsigned short* wt_f   = wt_i + (size_t)8 * 65536;
    unsigned short* wpk_th = wt_f + (size_t)131072;
    unsigned short* wpk_tl = wpk_th + (size_t)131072;
    unsigned short* wpk_ih = wpk_tl + (size_t)131072;
    unsigned short* wpk_il = wpk_ih + (size_t)131072;
    unsigned* idx_list = (unsigned*)(wpk_il + (size_t)131072);       // 16*NTOK
    float*    wgt_list = (float*)(idx_list + (size_t)16 * NTOK);     // 16*NTOK
    unsigned* cnt      = (unsigned*)(wgt_list + (size_t)16 * NTOK);  // 16*32
    unsigned* sel_e    = cnt + 512;                                  // 2*NTOK
    float2*   sel_w    = (float2*)(sel_e + (size_t)2 * NTOK);        // 2*NTOK

    prepW_kernel<<<dim3(16, 22), 256, 0, stream>>>(
        W_texp, W_iexp, W_mu_t, W_sg_t, W_mu_i, W_sg_i, W_fuse,
        wt_t, wt_i, wt_f, wpk_th, wpk_tl, wpk_ih, wpk_il);

    reparam_mfma_kernel<<<dim3(NTOK / 64, 4, 2), 256, 0, stream>>>(
        text, img, wpk_th, wpk_tl, wpk_ih, wpk_il,
        b_mu_t, b_sg_t, b_mu_i, b_sg_i,
        o_tmu, o_tsig, o_imu, o_isig);

    gate_kernel<<<dim3(NTOK / 4, 2), 256, 0, stream>>>(
        o_tmu, o_tsig, o_imu, o_isig, noise_t, noise_i,
        W_gate, b_gate, tzb, izb, sel_e, sel_w);

    compact_kernel<<<16, 1024, 0, stream>>>(
        sel_e, sel_w, idx_list, wgt_list, cnt);

    expert_sparse_kernel<<<dim3(100, 16, 2), 256, 0, stream>>>(
        tzb, izb, wt_t, wt_i, b_texp, b_iexp,
        idx_list, wgt_list, cnt, slot_t, slot_i);

    fusegemm_ln_kernel<<<NTOK / 32, 256, 0, stream>>>(
        slot_t, slot_i, wt_f, b_fuse, ln_g, ln_b, item, fusion);
}

// Round 15
// 137.657 us; speedup vs baseline: 1.0206x; 1.0206x over previous
//
#include <hip/hip_runtime.h>
#include <hip/hip_bf16.h>
#include <math.h>

#define NTOK 12800
#define HD 256
#define SOUT (NTOK * HD)

typedef __attribute__((ext_vector_type(8))) short short8_t;
typedef __attribute__((ext_vector_type(4))) float f32x4;

__device__ __forceinline__ unsigned short f2b(float f) {
    union { float f; unsigned u; } v; v.f = f;
    unsigned r = (v.u + 0x7FFFu + ((v.u >> 16) & 1u)) >> 16;
    return (unsigned short)r;
}
__device__ __forceinline__ float b2f(unsigned short s) {
    union { unsigned u; float f; } v; v.u = ((unsigned)s) << 16;
    return v.f;
}
__device__ __forceinline__ void glds16(const void* g, void* l) {
    __builtin_amdgcn_global_load_lds(
        (const __attribute__((address_space(1))) void*)g,
        (__attribute__((address_space(3))) void*)l, 16, 0, 0);
}
__device__ __forceinline__ short8_t add_bf16x8(short8_t a, short8_t b) {
    union { unsigned short u[8]; short8_t v; } ua, ub, r;
    ua.v = a; ub.v = b;
#pragma unroll
    for (int i = 0; i < 8; ++i) r.u[i] = f2b(b2f(ua.u[i]) + b2f(ub.u[i]));
    return r.v;
}
// read 8 fp32, emit bf16 hi + residual lo
__device__ __forceinline__ void split8(const float* s, short8_t* hi, short8_t* lo) {
    const float4 v0 = *reinterpret_cast<const float4*>(s);
    const float4 v1 = *reinterpret_cast<const float4*>(s + 4);
    const float x[8] = { v0.x, v0.y, v0.z, v0.w, v1.x, v1.y, v1.z, v1.w };
    union { unsigned short u[8]; short8_t v; } qh, ql;
#pragma unroll
    for (int c = 0; c < 8; ++c) {
        qh.u[c] = f2b(x[c]);
        ql.u[c] = f2b(x[c] - b2f(qh.u[c]));
    }
    *hi = qh.v;
    *lo = ql.v;
}

// ---------------------------------------------------------------------------
// prepW: transpose+convert weights fp32 [k][d] -> bf16 [d][k].
// ---------------------------------------------------------------------------
__global__ __launch_bounds__(256) void prepW_kernel(
    const float* __restrict__ W_texp, const float* __restrict__ W_iexp,
    const float* __restrict__ W_mu_t, const float* __restrict__ W_sg_t,
    const float* __restrict__ W_mu_i, const float* __restrict__ W_sg_i,
    const float* __restrict__ W_fuse,
    unsigned short* __restrict__ wt_t, unsigned short* __restrict__ wt_i,
    unsigned short* __restrict__ wt_f,
    unsigned short* __restrict__ wpk_th, unsigned short* __restrict__ wpk_tl,
    unsigned short* __restrict__ wpk_ih, unsigned short* __restrict__ wpk_il)
{
    const int z = blockIdx.y;
    const float* src;
    unsigned short* dsth;
    unsigned short* dstl = nullptr;
    int dstride = 256, koff = 0, rowoff = 0;
    if (z < 8)       { src = W_texp + (size_t)z * 65536;       dsth = wt_t + (size_t)z * 65536; }
    else if (z < 16) { src = W_iexp + (size_t)(z - 8) * 65536; dsth = wt_i + (size_t)(z - 8) * 65536; }
    else if (z == 16){ src = W_mu_t; dsth = wpk_th; dstl = wpk_tl; }
    else if (z == 17){ src = W_sg_t; dsth = wpk_th; dstl = wpk_tl; rowoff = 256; }
    else if (z == 18){ src = W_mu_i; dsth = wpk_ih; dstl = wpk_il; }
    else if (z == 19){ src = W_sg_i; dsth = wpk_ih; dstl = wpk_il; rowoff = 256; }
    else if (z == 20){ src = W_fuse;         dsth = wt_f; dstride = 512; koff = 0;   }
    else             { src = W_fuse + 65536; dsth = wt_f; dstride = 512; koff = 256; }

    const int tk = (blockIdx.x >> 2) * 64;
    const int td = (blockIdx.x & 3) * 64;
    __shared__ float T[64][68];
    const int t = threadIdx.x;
    {
        const int r = t >> 2, c0 = (t & 3) * 16;
        const float* s = &src[(size_t)(tk + r) * 256 + td + c0];
#pragma unroll
        for (int j = 0; j < 4; ++j)
            *reinterpret_cast<float4*>(&T[r][c0 + j * 4]) =
                *reinterpret_cast<const float4*>(&s[j * 4]);
    }
    __syncthreads();
    {
        const int d = t & 63, kc = (t >> 6) * 16;
        union { unsigned short s[16]; short8_t v[2]; } uh, ul;
#pragma unroll
        for (int j = 0; j < 16; ++j) {
            const float x = T[kc + j][d];
            uh.s[j] = f2b(x);
            ul.s[j] = f2b(x - b2f(uh.s[j]));
        }
        unsigned short* p = &dsth[(size_t)(rowoff + td + d) * dstride + koff + tk + kc];
        *reinterpret_cast<short8_t*>(p) = uh.v[0];
        *reinterpret_cast<short8_t*>(p + 8) = uh.v[1];
        if (dstl) {
            unsigned short* q = &dstl[(size_t)(rowoff + td + d) * 256 + tk + kc];
            *reinterpret_cast<short8_t*>(q) = ul.v[0];
            *reinterpret_cast<short8_t*>(q + 8) = ul.v[1];
        }
    }
}

// ---------------------------------------------------------------------------
// reparam (R10): packed [Wmu|Wsg], 64M x 128Npacked, 3-pass split-precision
// MFMA, in-register A split from fp32. grid (200, 4, 2).
// ---------------------------------------------------------------------------
__global__ __launch_bounds__(256) void reparam_mfma_kernel(
    const float* __restrict__ text, const float* __restrict__ img,
    const unsigned short* __restrict__ wpk_th, const unsigned short* __restrict__ wpk_tl,
    const unsigned short* __restrict__ wpk_ih, const unsigned short* __restrict__ wpk_il,
    const float* __restrict__ b_mu_t, const float* __restrict__ b_sg_t,
    const float* __restrict__ b_mu_i, const float* __restrict__ b_sg_i,
    float* __restrict__ o_tmu, float* __restrict__ o_tsig,
    float* __restrict__ o_imu, float* __restrict__ o_isig)
{
    const int mod = blockIdx.z;
    const float* A = mod ? img : text;
    const unsigned short* Wh = mod ? wpk_ih : wpk_th;
    const unsigned short* Wl = mod ? wpk_il : wpk_tl;
    const float* bmu = mod ? b_mu_i : b_mu_t;
    const float* bsg = mod ? b_sg_i : b_sg_t;
    float* omu = mod ? o_imu : o_tmu;
    float* osg = mod ? o_isig : o_tsig;

    __shared__ __align__(16) unsigned short AhS[2][4][64][8];
    __shared__ __align__(16) unsigned short AlS[2][4][64][8];
    __shared__ __align__(16) unsigned short BhS[2][4][128][8];
    __shared__ __align__(16) unsigned short BlS[2][4][128][8];

    const int tid = threadIdx.x;
    const int lane = tid & 63;
    const int w = tid >> 6;
    const int wr = w >> 1, wc = w & 1;
    const int lg = lane >> 4;
    const int lr = lane & 15;
    const int m0 = blockIdx.x * 64;
    const int n0 = blockIdx.y * 128;

    const int ar = tid >> 2, akc = tid & 3;
    const int bn = tid >> 1, bk0 = (tid & 1) * 2;

    {   // prologue: ks = 0
        short8_t h0, l0;
        split8(&A[(size_t)(m0 + ar) * HD + akc * 8], &h0, &l0);
        *reinterpret_cast<short8_t*>(&AhS[0][akc][ar][0]) = h0;
        *reinterpret_cast<short8_t*>(&AlS[0][akc][ar][0]) = l0;
#pragma unroll
        for (int j = 0; j < 2; ++j) {
            const int kc = bk0 + j;
            *reinterpret_cast<short8_t*>(&BhS[0][kc][bn][0]) =
                *reinterpret_cast<const short8_t*>(&Wh[(size_t)(n0 + bn) * HD + kc * 8]);
            *reinterpret_cast<short8_t*>(&BlS[0][kc][bn][0]) =
                *reinterpret_cast<const short8_t*>(&Wl[(size_t)(n0 + bn) * HD + kc * 8]);
        }
    }
    __syncthreads();

    f32x4 acc[2][4];
#pragma unroll
    for (int mi = 0; mi < 2; ++mi)
#pragma unroll
        for (int ni = 0; ni < 4; ++ni)
            acc[mi][ni] = (f32x4){0.f, 0.f, 0.f, 0.f};

    for (int ks = 0; ks < 8; ++ks) {
        const int cur = ks & 1;
        short8_t rah, ral, rbh[2], rbl[2];
        if (ks < 7) {
            const int k1 = (ks + 1) * 32;
            split8(&A[(size_t)(m0 + ar) * HD + k1 + akc * 8], &rah, &ral);
#pragma unroll
            for (int j = 0; j < 2; ++j) {
                const int kc = bk0 + j;
                rbh[j] = *reinterpret_cast<const short8_t*>(&Wh[(size_t)(n0 + bn) * HD + k1 + kc * 8]);
                rbl[j] = *reinterpret_cast<const short8_t*>(&Wl[(size_t)(n0 + bn) * HD + k1 + kc * 8]);
            }
        }
        short8_t ahf[2], alf[2], bhf[4], blf[4];
#pragma unroll
        for (int mi = 0; mi < 2; ++mi) {
            ahf[mi] = *reinterpret_cast<const short8_t*>(&AhS[cur][lg][wr * 32 + mi * 16 + lr][0]);
            alf[mi] = *reinterpret_cast<const short8_t*>(&AlS[cur][lg][wr * 32 + mi * 16 + lr][0]);
        }
#pragma unroll
        for (int ni = 0; ni < 4; ++ni) {
            bhf[ni] = *reinterpret_cast<const short8_t*>(&BhS[cur][lg][wc * 64 + ni * 16 + lr][0]);
            blf[ni] = *reinterpret_cast<const short8_t*>(&BlS[cur][lg][wc * 64 + ni * 16 + lr][0]);
        }
#pragma unroll
        for (int mi = 0; mi < 2; ++mi)
#pragma unroll
            for (int ni = 0; ni < 4; ++ni) {
                acc[mi][ni] = __builtin_amdgcn_mfma_f32_16x16x32_bf16(ahf[mi], bhf[ni], acc[mi][ni], 0, 0, 0);
                acc[mi][ni] = __builtin_amdgcn_mfma_f32_16x16x32_bf16(ahf[mi], blf[ni], acc[mi][ni], 0, 0, 0);
                acc[mi][ni] = __builtin_amdgcn_mfma_f32_16x16x32_bf16(alf[mi], bhf[ni], acc[mi][ni], 0, 0, 0);
            }
        if (ks < 7) {
            const int nxt = cur ^ 1;
            *reinterpret_cast<short8_t*>(&AhS[nxt][akc][ar][0]) = rah;
            *reinterpret_cast<short8_t*>(&AlS[nxt][akc][ar][0]) = ral;
#pragma unroll
            for (int j = 0; j < 2; ++j) {
                const int kc = bk0 + j;
                *reinterpret_cast<short8_t*>(&BhS[nxt][kc][bn][0]) = rbh[j];
                *reinterpret_cast<short8_t*>(&BlS[nxt][kc][bn][0]) = rbl[j];
            }
        }
        __syncthreads();
    }

    const bool is_sg = (n0 >= 256);
    float bv[4];
    int cc[4];
#pragma unroll
    for (int ni = 0; ni < 4; ++ni) {
        const int dpk = n0 + wc * 64 + ni * 16 + lr;
        cc[ni] = is_sg ? dpk - 256 : dpk;
        bv[ni] = is_sg ? bsg[cc[ni]] : bmu[cc[ni]];
    }
    float* outp = is_sg ? osg : omu;
#pragma unroll
    for (int mi = 0; mi < 2; ++mi)
#pragma unroll
        for (int r = 0; r < 4; ++r) {
            const int row = m0 + wr * 32 + mi * 16 + lg * 4 + r;
#pragma unroll
            for (int ni = 0; ni < 4; ++ni) {
                const float v = acc[mi][ni][r] + bv[ni];
                outp[(size_t)row * HD + cc[ni]] = is_sg ? expf(v) : v;
            }
        }
}

// ---------------------------------------------------------------------------
// gating (R10): z = mu + sig*noise -> logits -> softmax -> top2. No atomics.
// ---------------------------------------------------------------------------
__global__ __launch_bounds__(256) void gate_kernel(
    const float* __restrict__ o_tmu, const float* __restrict__ o_tsig,
    const float* __restrict__ o_imu, const float* __restrict__ o_isig,
    const float* __restrict__ noise_t, const float* __restrict__ noise_i,
    const float* __restrict__ Wg, const float* __restrict__ bg,
    unsigned short* __restrict__ tzb, unsigned short* __restrict__ izb,
    unsigned* __restrict__ sel_e, float2* __restrict__ sel_w)
{
    const int mod = blockIdx.y;
    const float* mu    = mod ? o_imu  : o_tmu;
    const float* sig   = mod ? o_isig : o_tsig;
    const float* noise = mod ? noise_i : noise_t;
    unsigned short* zb = mod ? izb : tzb;

    const int lane = threadIdx.x & 63;
    const int n = blockIdx.x * 4 + (threadIdx.x >> 6);
    const size_t off = (size_t)n * HD + lane * 4;
    const float4 m4 = *reinterpret_cast<const float4*>(&mu[off]);
    const float4 s4 = *reinterpret_cast<const float4*>(&sig[off]);
    const float4 n4 = *reinterpret_cast<const float4*>(&noise[off]);
    const float zz[4] = { fmaf(s4.x, n4.x, m4.x), fmaf(s4.y, n4.y, m4.y),
                          fmaf(s4.z, n4.z, m4.z), fmaf(s4.w, n4.w, m4.w) };
    ushort4 zb4;
    zb4.x = f2b(zz[0]); zb4.y = f2b(zz[1]); zb4.z = f2b(zz[2]); zb4.w = f2b(zz[3]);
    *reinterpret_cast<ushort4*>(&zb[off]) = zb4;

    float lg[8];
#pragma unroll
    for (int e = 0; e < 8; ++e) lg[e] = 0.f;
#pragma unroll
    for (int i = 0; i < 4; ++i) {
        const float* wr = &Wg[(size_t)(lane * 4 + i) * 8];
        const float4 w0 = *reinterpret_cast<const float4*>(wr);
        const float4 w1 = *reinterpret_cast<const float4*>(wr + 4);
        lg[0] = fmaf(zz[i], w0.x, lg[0]); lg[1] = fmaf(zz[i], w0.y, lg[1]);
        lg[2] = fmaf(zz[i], w0.z, lg[2]); lg[3] = fmaf(zz[i], w0.w, lg[3]);
        lg[4] = fmaf(zz[i], w1.x, lg[4]); lg[5] = fmaf(zz[i], w1.y, lg[5]);
        lg[6] = fmaf(zz[i], w1.z, lg[6]); lg[7] = fmaf(zz[i], w1.w, lg[7]);
    }
#pragma unroll
    for (int off2 = 32; off2; off2 >>= 1)
#pragma unroll
        for (int e = 0; e < 8; ++e) lg[e] += __shfl_down(lg[e], off2);

    if (lane == 0) {
        float m = -1e30f;
#pragma unroll
        for (int e = 0; e < 8; ++e) { lg[e] += bg[e]; m = fmaxf(m, lg[e]); }
        float p[8], s = 0.f;
#pragma unroll
        for (int e = 0; e < 8; ++e) { p[e] = expf(lg[e] - m); s += p[e]; }
        const float inv_s = 1.f / s;
#pragma unroll
        for (int e = 0; e < 8; ++e) p[e] *= inv_s;
        int e1 = 0;
#pragma unroll
        for (int e = 1; e < 8; ++e) if (p[e] > p[e1]) e1 = e;
        int e2 = (e1 == 0) ? 1 : 0;
#pragma unroll
        for (int e = 0; e < 8; ++e) if (e != e1 && p[e] > p[e2]) e2 = e;
        const float denom = 1.f / (p[e1] + p[e2] + 1e-8f);
        sel_e[(size_t)mod * NTOK + n] = (unsigned)e1 | ((unsigned)e2 << 8);
        sel_w[(size_t)mod * NTOK + n] = make_float2(p[e1] * denom, p[e2] * denom);
    }
}

// ---------------------------------------------------------------------------
// compact (R10): ballot + LDS wave-prefix compaction, no atomics.
// ---------------------------------------------------------------------------
__global__ __launch_bounds__(1024) void compact_kernel(
    const unsigned* __restrict__ sel_e, const float2* __restrict__ sel_w,
    unsigned* __restrict__ idx_list, float* __restrict__ wgt_list,
    unsigned* __restrict__ cnt)
{
    const int seg = blockIdx.x;          // mod*8 + e
    const int mod = seg >> 3;
    const unsigned e = (unsigned)(seg & 7);
    const int tid = threadIdx.x;
    const int wid = tid >> 6, lane = tid & 63;
    __shared__ unsigned wsum[16];

    unsigned off = 0;
    unsigned* dst_i = idx_list + (size_t)seg * NTOK;
    float* dst_w = wgt_list + (size_t)seg * NTOK;

    for (int chunk = 0; chunk < NTOK; chunk += 1024) {
        const int n = chunk + tid;
        const bool valid = (n < NTOK);
        unsigned se = 0;
        float2 wv = make_float2(0.f, 0.f);
        if (valid) {
            se = sel_e[(size_t)mod * NTOK + n];
            wv = sel_w[(size_t)mod * NTOK + n];
        }
#pragma unroll
        for (int slot = 0; slot < 2; ++slot) {
            const unsigned es = slot ? ((se >> 8) & 0xffu) : (se & 0xffu);
            const bool pred = valid && (es == e);
            const unsigned long long mask = __ballot(pred);
            if (lane == 0) wsum[wid] = (unsigned)__popcll(mask);
            __syncthreads();
            unsigned prefix = 0, total = 0;
#pragma unroll
            for (int wI = 0; wI < 16; ++wI) {
                const unsigned c = wsum[wI];
                if (wI < wid) prefix += c;
                total += c;
            }
            if (pred) {
                const unsigned long long lt = ((unsigned long long)1 << lane) - 1ull;
                const unsigned pos = off + prefix + (unsigned)__popcll(mask & lt);
                dst_i[pos] = (unsigned)(n * 2 + slot);
                dst_w[pos] = slot ? wv.y : wv.x;
            }
            off += total;
            __syncthreads();
        }
    }
    if (tid == 0) cnt[seg * 32] = off;
}

// ---------------------------------------------------------------------------
// sparse experts (R10): gathered grouped-GEMM, glds dbuf staging.
// ---------------------------------------------------------------------------
__global__ __launch_bounds__(256) void expert_sparse_kernel(
    const unsigned short* __restrict__ tzb, const unsigned short* __restrict__ izb,
    const unsigned short* __restrict__ wt_t, const unsigned short* __restrict__ wt_i,
    const float* __restrict__ bx_t, const float* __restrict__ bx_i,
    const unsigned* __restrict__ idx_list, const float* __restrict__ wgt_list,
    const unsigned* __restrict__ cnt,
    unsigned short* __restrict__ slot_t, unsigned short* __restrict__ slot_i)
{
    const int chunk = blockIdx.x;
    const int e  = blockIdx.y >> 1;
    const int nh = blockIdx.y & 1;
    const int mod = blockIdx.z;
    const int seg = mod * 8 + e;
    const unsigned cnt_e = cnt[seg * 32];
    if ((unsigned)(chunk * 128) >= cnt_e) return;

    const unsigned short* Zb = mod ? izb : tzb;
    const unsigned short* Wt = mod ? wt_i : wt_t;
    const float* bx = mod ? bx_i : bx_t;
    unsigned short* outp = mod ? slot_i : slot_t;
    const int n0 = nh * 128;
    const size_t sb = (size_t)seg * NTOK + (size_t)chunk * 128;

    __shared__ __align__(16) unsigned short Ab[2][512][8];
    __shared__ __align__(16) unsigned short Bb[2][512][8];
    __shared__ float gw[128];
    __shared__ unsigned il[128];

    const int tid = threadIdx.x;
    const int lane = tid & 63;
    const int w = tid >> 6;
    const int wr = w >> 1, wc = w & 1;
    const int lg = lane >> 4;
    const int lr = lane & 15;

    if (tid < 128) {
        const bool v = (unsigned)(chunk * 128 + tid) < cnt_e;
        il[tid] = v ? idx_list[sb + tid] : (unsigned)(2 * NTOK);
        gw[tid] = v ? wgt_list[sb + tid] : 0.f;
    }

    const int c0 = w * 64 + lane;
    const int row0 = c0 >> 2,         kc0 = c0 & 3;
    const int row1 = (c0 + 256) >> 2, kc1 = (c0 + 256) & 3;
    const unsigned i0 = ((unsigned)(chunk * 128 + row0) < cnt_e)
                        ? idx_list[sb + row0] : (unsigned)(2 * NTOK);
    const unsigned i1 = ((unsigned)(chunk * 128 + row1) < cnt_e)
                        ? idx_list[sb + row1] : (unsigned)(2 * NTOK);
    const size_t atok0 = (size_t)(i0 >> 1) * HD;
    const size_t atok1 = (size_t)(i1 >> 1) * HD;
    const unsigned short* We_ = Wt + (size_t)e * 65536 + (size_t)n0 * HD;

#define SSTAGE(buf, ks_)                                                       \
    {                                                                          \
        glds16(&Zb[atok0 + (ks_) * 32 + kc0 * 8], &Ab[buf][w * 64][0]);        \
        glds16(&Zb[atok1 + (ks_) * 32 + kc1 * 8], &Ab[buf][256 + w * 64][0]);  \
        glds16(&We_[(size_t)row0 * HD + (ks_) * 32 + kc0 * 8],                 \
               &Bb[buf][w * 64][0]);                                           \
        glds16(&We_[(size_t)row1 * HD + (ks_) * 32 + kc1 * 8],                 \
               &Bb[buf][256 + w * 64][0]);                                     \
    }

    SSTAGE(0, 0);
    __syncthreads();

    f32x4 acc[4][4];
#pragma unroll
    for (int mi = 0; mi < 4; ++mi)
#pragma unroll
        for (int ni = 0; ni < 4; ++ni)
            acc[mi][ni] = (f32x4){0.f, 0.f, 0.f, 0.f};

    for (int ks = 0; ks < 8; ++ks) {
        const int cur = ks & 1;
        if (ks < 7) SSTAGE(cur ^ 1, ks + 1);
        short8_t af[4], bf[4];
#pragma unroll
        for (int mi = 0; mi < 4; ++mi)
            af[mi] = *reinterpret_cast<const short8_t*>(
                &Ab[cur][(wr * 64 + mi * 16 + lr) * 4 + lg][0]);
#pragma unroll
        for (int ni = 0; ni < 4; ++ni)
            bf[ni] = *reinterpret_cast<const short8_t*>(
                &Bb[cur][(wc * 64 + ni * 16 + lr) * 4 + lg][0]);
#pragma unroll
        for (int mi = 0; mi < 4; ++mi)
#pragma unroll
            for (int ni = 0; ni < 4; ++ni)
                acc[mi][ni] = __builtin_amdgcn_mfma_f32_16x16x32_bf16(
                    af[mi], bf[ni], acc[mi][ni], 0, 0, 0);
        __syncthreads();
    }
#undef SSTAGE

    float bv[4];
#pragma unroll
    for (int ni = 0; ni < 4; ++ni)
        bv[ni] = bx[(size_t)e * HD + n0 + wc * 64 + ni * 16 + lr];
#pragma unroll
    for (int mi = 0; mi < 4; ++mi)
#pragma unroll
        for (int r = 0; r < 4; ++r) {
            const int row_local = wr * 64 + mi * 16 + lg * 4 + r;
            const float wv = gw[row_local];
            const size_t tb = (size_t)il[row_local] * HD;
#pragma unroll
            for (int ni = 0; ni < 4; ++ni)
                outp[tb + n0 + wc * 64 + ni * 16 + lr] =
                    f2b(wv * (acc[mi][ni][r] + bv[ni]));
        }
}

// ---------------------------------------------------------------------------
// fuse GEMM (R10): A = slot0 + slot1 summed during staging, K = 512.
// ---------------------------------------------------------------------------
__global__ __launch_bounds__(256) void fusegemm_mfma_kernel(
    const unsigned short* __restrict__ slot_t, const unsigned short* __restrict__ slot_i,
    const unsigned short* __restrict__ wtf, const float* __restrict__ bfuse,
    float* __restrict__ fused)
{
    __shared__ __align__(16) unsigned short AS[2][8][64][8];
    __shared__ __align__(16) unsigned short BS[2][8][128][8];

    const int tid = threadIdx.x;
    const int lane = tid & 63;
    const int w = tid >> 6;
    const int wr = w >> 1, wc = w & 1;
    const int lg = lane >> 4;
    const int lr = lane & 15;
    const int m0 = blockIdx.x * 64;
    const int n0 = blockIdx.y * 128;

    const int ar = tid >> 2, akc0 = (tid & 3) * 2;
    const int bn = tid >> 1, bkc0 = (tid & 1) * 4;
    const size_t tb = (size_t)(m0 + ar) * 2 * HD;

    {
#pragma unroll
        for (int j = 0; j < 2; ++j) {
            const int kc = akc0 + j;
            const short8_t s0 = *reinterpret_cast<const short8_t*>(&slot_t[tb + kc * 8]);
            const short8_t s1 = *reinterpret_cast<const short8_t*>(&slot_t[tb + HD + kc * 8]);
            *reinterpret_cast<short8_t*>(&AS[0][kc][ar][0]) = add_bf16x8(s0, s1);
        }
#pragma unroll
        for (int j = 0; j < 4; ++j) {
            const int kc = bkc0 + j;
            *reinterpret_cast<short8_t*>(&BS[0][kc][bn][0]) =
                *reinterpret_cast<const short8_t*>(&wtf[(size_t)(n0 + bn) * 512 + kc * 8]);
        }
    }
    __syncthreads();

    f32x4 acc[2][4];
#pragma unroll
    for (int mi = 0; mi < 2; ++mi)
#pragma unroll
        for (int ni = 0; ni < 4; ++ni)
            acc[mi][ni] = (f32x4){0.f, 0.f, 0.f, 0.f};

    for (int ks = 0; ks < 8; ++ks) {
        const int cur = ks & 1;
        short8_t ra[2], rbv[4];
        if (ks < 7) {
            const int ks2 = ks + 1;
            const unsigned short* sp = (ks2 < 4) ? slot_t : slot_i;
            const int kloc = (ks2 & 3) * 64;
#pragma unroll
            for (int j = 0; j < 2; ++j) {
                const int kc = akc0 + j;
                const short8_t s0 = *reinterpret_cast<const short8_t*>(
                    &sp[tb + kloc + kc * 8]);
                const short8_t s1 = *reinterpret_cast<const short8_t*>(
                    &sp[tb + HD + kloc + kc * 8]);
                ra[j] = add_bf16x8(s0, s1);
            }
#pragma unroll
            for (int j = 0; j < 4; ++j) {
                const int kc = bkc0 + j;
                rbv[j] = *reinterpret_cast<const short8_t*>(
                    &wtf[(size_t)(n0 + bn) * 512 + ks2 * 64 + kc * 8]);
            }
        }
#pragma unroll
        for (int s = 0; s < 2; ++s) {
            short8_t af[2], bf[4];
#pragma unroll
            for (int mi = 0; mi < 2; ++mi)
                af[mi] = *reinterpret_cast<const short8_t*>(
                    &AS[cur][s * 4 + lg][wr * 32 + mi * 16 + lr][0]);
#pragma unroll
            for (int ni = 0; ni < 4; ++ni)
                bf[ni] = *reinterpret_cast<const short8_t*>(
                    &BS[cur][s * 4 + lg][wc * 64 + ni * 16 + lr][0]);
#pragma unroll
            for (int mi = 0; mi < 2; ++mi)
#pragma unroll
                for (int ni = 0; ni < 4; ++ni)
                    acc[mi][ni] = __builtin_amdgcn_mfma_f32_16x16x32_bf16(
                        af[mi], bf[ni], acc[mi][ni], 0, 0, 0);
        }
        if (ks < 7) {
            const int nxt = cur ^ 1;
#pragma unroll
            for (int j = 0; j < 2; ++j)
                *reinterpret_cast<short8_t*>(&AS[nxt][akc0 + j][ar][0]) = ra[j];
#pragma unroll
            for (int j = 0; j < 4; ++j)
                *reinterpret_cast<short8_t*>(&BS[nxt][bkc0 + j][bn][0]) = rbv[j];
        }
        __syncthreads();
    }

    float bv[4];
    int cc[4];
#pragma unroll
    for (int ni = 0; ni < 4; ++ni) {
        cc[ni] = n0 + wc * 64 + ni * 16 + lr;
        bv[ni] = bfuse[cc[ni]];
    }
#pragma unroll
    for (int mi = 0; mi < 2; ++mi)
#pragma unroll
        for (int r = 0; r < 4; ++r) {
            const int row = m0 + wr * 32 + mi * 16 + lg * 4 + r;
#pragma unroll
            for (int ni = 0; ni < 4; ++ni)
                fused[(size_t)row * HD + cc[ni]] = acc[mi][ni][r] + bv[ni];
        }
}

// ---------------------------------------------------------------------------
// LN -> ReLU -> +item (R10)
// ---------------------------------------------------------------------------
__global__ __launch_bounds__(256) void ln_relu_res_kernel(
    const float* __restrict__ fused, const float* __restrict__ g,
    const float* __restrict__ b, const float* __restrict__ item,
    float* __restrict__ fusion)
{
    const int lane = threadIdx.x & 63;
    const int n = blockIdx.x * 4 + (threadIdx.x >> 6);
    const size_t off = (size_t)n * HD + lane * 4;
    const float4 x = *reinterpret_cast<const float4*>(&fused[off]);
    float s = x.x + x.y + x.z + x.w;
    float ss = x.x * x.x + x.y * x.y + x.z * x.z + x.w * x.w;
#pragma unroll
    for (int o = 32; o; o >>= 1) { s += __shfl_xor(s, o); ss += __shfl_xor(ss, o); }
    const float mean = s * (1.f / 256.f);
    const float var = ss * (1.f / 256.f) - mean * mean;
    const float rstd = rsqrtf(var + 1e-5f);
    const float4 gg = *reinterpret_cast<const float4*>(&g[lane * 4]);
    const float4 bb = *reinterpret_cast<const float4*>(&b[lane * 4]);
    const float4 it = *reinterpret_cast<const float4*>(&item[off]);
    float4 o4;
    o4.x = fmaxf((x.x - mean) * rstd * gg.x + bb.x, 0.f) + it.x;
    o4.y = fmaxf((x.y - mean) * rstd * gg.y + bb.y, 0.f) + it.y;
    o4.z = fmaxf((x.z - mean) * rstd * gg.z + bb.z, 0.f) + it.z;
    o4.w = fmaxf((x.w - mean) * rstd * gg.w + bb.w, 0.f) + it.w;
    *reinterpret_cast<float4*>(&fusion[off]) = o4;
}

// ---------------------------------------------------------------------------
extern "C" void kernel_launch(void* const* d_in, const int* in_sizes, int n_in,
                              void* d_out, int out_size, void* d_ws, size_t ws_size,
                              hipStream_t stream)
{
    const float* text    = (const float*)d_in[0];
    const float* img     = (const float*)d_in[1];
    const float* item    = (const float*)d_in[2];
    const float* noise_t = (const float*)d_in[3];
    const float* noise_i = (const float*)d_in[4];
    const float* W_mu_t  = (const float*)d_in[5];
    const float* b_mu_t  = (const float*)d_in[6];
    const float* W_sg_t  = (const float*)d_in[7];
    const float* b_sg_t  = (const float*)d_in[8];
    const float* W_mu_i  = (const float*)d_in[9];
    const float* b_mu_i  = (const float*)d_in[10];
    const float* W_sg_i  = (const float*)d_in[11];
    const float* b_sg_i  = (const float*)d_in[12];
    const float* W_gate  = (const float*)d_in[13];
    const float* b_gate  = (const float*)d_in[14];
    const float* W_texp  = (const float*)d_in[15];
    const float* b_texp  = (const float*)d_in[16];
    const float* W_iexp  = (const float*)d_in[17];
    const float* b_iexp  = (const float*)d_in[18];
    const float* W_fuse  = (const float*)d_in[19];
    const float* b_fuse  = (const float*)d_in[20];
    const float* ln_g    = (const float*)d_in[21];
    const float* ln_b    = (const float*)d_in[22];

    float* out    = (float*)d_out;
    float* fusion = out;
    float* o_tmu  = out + (size_t)SOUT;
    float* o_tsig = out + (size_t)2 * SOUT;
    float* o_imu  = out + (size_t)3 * SOUT;
    float* o_isig = out + (size_t)4 * SOUT;

    const size_t SLOTPAD = (size_t)(2 * NTOK + 256) * HD;
    unsigned short* slot_t = (unsigned short*)d_ws;
    unsigned short* slot_i = slot_t + SLOTPAD;
    unsigned short* tzb    = slot_i + SLOTPAD;
    unsigned short* izb    = tzb + (size_t)SOUT;
    unsigned short* wt_t   = izb + (size_t)SOUT;
    unsigned short* wt_i   = wt_t + (size_t)8 * 65536;
    unsigned short* wt_f   = wt_i + (size_t)8 * 65536;
    unsigned short* wpk_th = wt_f + (size_t)131072;
    unsigned short* wpk_tl = wpk_th + (size_t)131072;
    unsigned short* wpk_ih = wpk_tl + (size_t)131072;
    unsigned short* wpk_il = wpk_ih + (size_t)131072;
    unsigned* idx_list = (unsigned*)(wpk_il + (size_t)131072);       // 16*NTOK
    float*    wgt_list = (float*)(idx_list + (size_t)16 * NTOK);     // 16*NTOK
    unsigned* cnt      = (unsigned*)(wgt_list + (size_t)16 * NTOK);  // 16*32
    unsigned* sel_e    = cnt + 512;                                  // 2*NTOK
    float2*   sel_w    = (float2*)(sel_e + (size_t)2 * NTOK);        // 2*NTOK

    float* fused = (float*)tzb;  // tzb/izb region is dead by fusegemm time

    prepW_kernel<<<dim3(16, 22), 256, 0, stream>>>(
        W_texp, W_iexp, W_mu_t, W_sg_t, W_mu_i, W_sg_i, W_fuse,
        wt_t, wt_i, wt_f, wpk_th, wpk_tl, wpk_ih, wpk_il);

    reparam_mfma_kernel<<<dim3(NTOK / 64, 4, 2), 256, 0, stream>>>(
        text, img, wpk_th, wpk_tl, wpk_ih, wpk_il,
        b_mu_t, b_sg_t, b_mu_i, b_sg_i,
        o_tmu, o_tsig, o_imu, o_isig);

    gate_kernel<<<dim3(NTOK / 4, 2), 256, 0, stream>>>(
        o_tmu, o_tsig, o_imu, o_isig, noise_t, noise_i,
        W_gate, b_gate, tzb, izb, sel_e, sel_w);

    compact_kernel<<<16, 1024, 0, stream>>>(
        sel_e, sel_w, idx_list, wgt_list, cnt);

    expert_sparse_kernel<<<dim3(100, 16, 2), 256, 0, stream>>>(
        tzb, izb, wt_t, wt_i, b_texp, b_iexp,
        idx_list, wgt_list, cnt, slot_t, slot_i);

    fusegemm_mfma_kernel<<<dim3(NTOK / 64, 2), 256, 0, stream>>>(
        slot_t, slot_i, wt_f, b_fuse, fused);

    ln_relu_res_kernel<<<NTOK / 4, 256, 0, stream>>>(fused, ln_g, ln_b, item, fusion);
}